// Round 2
// baseline (9554.730 us; speedup 1.0000x reference)
//
#include <hip/hip_runtime.h>

// LSTM B=64 T=2048 D=H=256.
// lstm_proj: xg[t][bg][j][16b] = x@W_i + bias (fp16, MFMA f16), block-contiguous layout.
// lstm_recur: persistent scan, 4 blocks x 16 batch rows. Weight residency per block (CU):
//   gate i (cols   0..255): fp8 e4m3 in VGPRs (2 tiles/wave, 32 regs)
//   gate f (cols 256..511): fp16 in VGPRs (2 tiles/wave, 64 regs)
//   gate g (cols 512..767): fp16 in VGPRs (2 tiles/wave, 64 regs)   <- was LDS (16 b128 reads/step)
//   gate o (cols 768..1023): fp8 e4m3 in LDS (64 KB, 2x b64 reads/kt) <- was VGPRs
// Rationale: MFMA phase was LDS-read-pipe bound (~2700 cyc/CU/step of ds_read vs
// ~2050 cyc of MFMA). Moving the b128-heavy g-gate to regs and the cheap-to-read
// fp8 o-gate to LDS cuts LDS pipe to ~1900 cyc/CU/step.
// c-state lane-private (8 VGPRs). h double-buffered in LDS as fp16 AND fp8:
//   step tt reads buf[tt&1], writes buf[tt&1 ^ 1] -> ONE raw s_barrier per step with
//   lgkmcnt(0)-only drain (no vmcnt drain of global out-stores / xq-loads).
// MFMA 16x16x32 (f16 and fp8_fp8): A[m=lane&15][k=(lane>>4)*8+j],
//   B[k][n=lane&15], C row=(lane>>4)*4+reg, col=lane&15.

#define T_ALL 2048
#define NBATCH 64
#define HD 256
#define NG 1024
#define HS_N ((size_t)NBATCH * T_ALL * HD)

typedef _Float16 h8 __attribute__((ext_vector_type(8)));
typedef _Float16 h4 __attribute__((ext_vector_type(4)));
typedef float f4 __attribute__((ext_vector_type(4)));

#define SMEM_W8 65536                 // o-gate fp8: [16 q][8 kt][64 lanes][8 bytes]
#define SMEM_H 8448                   // h fp16: 16 rows x 264 halfs (16B row pad)
#define SMEM_H8 4224                  // h fp8:  16 rows x 264 bytes
#define SMEM_TOTAL (SMEM_W8 + 2 * SMEM_H + 2 * SMEM_H8)   // 90880 <= 163840

__device__ __forceinline__ float sigf(float x) {
  return __builtin_amdgcn_rcpf(1.f + __expf(-x));
}
__device__ __forceinline__ float tanh_f(float x) {
  return 2.f * __builtin_amdgcn_rcpf(1.f + __expf(-2.f * x)) - 1.f;
}
__device__ __forceinline__ unsigned char to_fp8(float x) {
  return (unsigned char)(__builtin_amdgcn_cvt_pk_fp8_f32(x, x, 0, false) & 0xFF);
}

// ---------------- input projection: one block per timestep ----------------
__global__ __launch_bounds__(256, 2) void lstm_proj(
    const float* __restrict__ x, const float* __restrict__ Wi,
    const float* __restrict__ bias, _Float16* __restrict__ xg, int t0)
{
  const int t = t0 + blockIdx.x;
  const int tid = threadIdx.x;
  const int w = tid >> 6, L = tid & 63;
  const int n = L & 15, quad = L >> 4;

  // B-fragments: x^T[k][b], reused across all j tiles (32 frags = 128 VGPRs)
  h8 bx[8][4];
#pragma unroll
  for (int kt = 0; kt < 8; ++kt) {
#pragma unroll
    for (int bt = 0; bt < 4; ++bt) {
      const int b = bt * 16 + n, k = kt * 32 + quad * 8;
      const float* p = x + ((size_t)b * T_ALL + t) * HD + k;
      f4 lo = *(const f4*)p, hi = *(const f4*)(p + 4);
      h8 f;
      f[0] = (_Float16)lo[0]; f[1] = (_Float16)lo[1];
      f[2] = (_Float16)lo[2]; f[3] = (_Float16)lo[3];
      f[4] = (_Float16)hi[0]; f[5] = (_Float16)hi[1];
      f[6] = (_Float16)hi[2]; f[7] = (_Float16)hi[3];
      bx[kt][bt] = f;
    }
  }

  for (int i = 0; i < 16; ++i) {       // wave w owns j-tiles w*16 .. w*16+15
    const int jt = w * 16 + i;
    float bv0 = bias[jt * 16 + quad * 4 + 0];
    float bv1 = bias[jt * 16 + quad * 4 + 1];
    float bv2 = bias[jt * 16 + quad * 4 + 2];
    float bv3 = bias[jt * 16 + quad * 4 + 3];
    f4 acc[4];
#pragma unroll
    for (int bt = 0; bt < 4; ++bt) {
      acc[bt][0] = bv0; acc[bt][1] = bv1; acc[bt][2] = bv2; acc[bt][3] = bv3;
    }
#pragma unroll
    for (int kt = 0; kt < 8; ++kt) {
      const int j = jt * 16 + n, kb = kt * 32 + quad * 8;
      h8 a;   // A = Wi^T: A[m=j][k=d] = Wi[d][j]
#pragma unroll
      for (int jj = 0; jj < 8; ++jj) a[jj] = (_Float16)Wi[(size_t)(kb + jj) * NG + j];
#pragma unroll
      for (int bt = 0; bt < 4; ++bt)
        acc[bt] = __builtin_amdgcn_mfma_f32_16x16x32_f16(a, bx[kt][bt], acc[bt], 0, 0, 0);
    }
#pragma unroll
    for (int bt = 0; bt < 4; ++bt) {
#pragma unroll
      for (int r = 0; r < 4; ++r) {
        const int j = jt * 16 + quad * 4 + r;   // gate col
        xg[(((size_t)blockIdx.x * 4 + bt) * NG + j) * 16 + n] = (_Float16)acc[bt][r];
      }
    }
  }
}

// ---------------- persistent recurrence: 4 blocks x 16 batch rows ----------------
__global__ __launch_bounds__(512, 2) void lstm_recur(
    const _Float16* __restrict__ xg, const float* __restrict__ Wh,
    float* __restrict__ out, _Float16* __restrict__ ws_h, float* __restrict__ ws_c,
    int t0, int CT)
{
  extern __shared__ char smem[];
  unsigned char* w8_lds = (unsigned char*)smem;                   // o-gate fp8 tiles

  const int tid = threadIdx.x;
  const int w = tid >> 6, L = tid & 63;
  const int n = L & 15, quad = L >> 4;
  const int b_base = blockIdx.x * 16;

  // ---- load resident weights (one-time) ----
  h8  bF[2][8];                    // f gate fp16: 64 VGPRs
  h8  bG[2][8];                    // g gate fp16: 64 VGPRs
  long bI[2][8];                   // i gate fp8 packed: 32 VGPRs
#pragma unroll
  for (int qi = 0; qi < 2; ++qi) {
    const int q = 2 * w + qi;
    for (int kt = 0; kt < 8; ++kt) {
      const int kb = kt * 32 + quad * 8;
      { // f gate, fp16 regs
        const int j = 256 + q * 16 + n;
        h8 f;
#pragma unroll
        for (int jj = 0; jj < 8; ++jj) f[jj] = (_Float16)Wh[(size_t)(kb + jj) * NG + j];
        bF[qi][kt] = f;
      }
      { // g gate, fp16 regs
        const int j = 512 + q * 16 + n;
        h8 f;
#pragma unroll
        for (int jj = 0; jj < 8; ++jj) f[jj] = (_Float16)Wh[(size_t)(kb + jj) * NG + j];
        bG[qi][kt] = f;
      }
      { // i gate, fp8 regs
        const int j = 0 + q * 16 + n;
        unsigned lo = 0, hi = 0;
        lo = __builtin_amdgcn_cvt_pk_fp8_f32(Wh[(size_t)(kb + 0) * NG + j], Wh[(size_t)(kb + 1) * NG + j], lo, false);
        lo = __builtin_amdgcn_cvt_pk_fp8_f32(Wh[(size_t)(kb + 2) * NG + j], Wh[(size_t)(kb + 3) * NG + j], lo, true);
        hi = __builtin_amdgcn_cvt_pk_fp8_f32(Wh[(size_t)(kb + 4) * NG + j], Wh[(size_t)(kb + 5) * NG + j], hi, false);
        hi = __builtin_amdgcn_cvt_pk_fp8_f32(Wh[(size_t)(kb + 6) * NG + j], Wh[(size_t)(kb + 7) * NG + j], hi, true);
        bI[qi][kt] = (long)(((unsigned long)hi << 32) | (unsigned long)lo);
      }
      { // o gate, fp8 -> LDS
        const int j = 768 + q * 16 + n;
        unsigned lo = 0, hi = 0;
        lo = __builtin_amdgcn_cvt_pk_fp8_f32(Wh[(size_t)(kb + 0) * NG + j], Wh[(size_t)(kb + 1) * NG + j], lo, false);
        lo = __builtin_amdgcn_cvt_pk_fp8_f32(Wh[(size_t)(kb + 2) * NG + j], Wh[(size_t)(kb + 3) * NG + j], lo, true);
        hi = __builtin_amdgcn_cvt_pk_fp8_f32(Wh[(size_t)(kb + 4) * NG + j], Wh[(size_t)(kb + 5) * NG + j], hi, false);
        hi = __builtin_amdgcn_cvt_pk_fp8_f32(Wh[(size_t)(kb + 6) * NG + j], Wh[(size_t)(kb + 7) * NG + j], hi, true);
        *(unsigned long*)(w8_lds + ((size_t)(q * 8 + kt) * 64 + L) * 8) =
            ((unsigned long)hi << 32) | (unsigned long)lo;
      }
    }
  }

  // ---- state init / restore (into buffer 0: read buffer of step tt=0) ----
  _Float16* h0 = (_Float16*)(smem + SMEM_W8);
  unsigned char* h80 = (unsigned char*)(smem + SMEM_W8 + 2 * SMEM_H);
  float creg[8];                    // lane-private c: row=quad*4+r, col=(2w+qi)*16+n
  if (t0 == 0) {
    for (int i = tid; i < 16 * 264; i += 512) h0[i] = (_Float16)0.f;
    for (int i = tid * 4; i < 16 * 264; i += 512 * 4) *(unsigned*)(h80 + i) = 0u;
#pragma unroll
    for (int i = 0; i < 8; ++i) creg[i] = 0.f;
  } else {
    const int idx = tid * 8, r = idx >> 8, c = idx & 255;
    h8 hv = *(const h8*)(ws_h + (size_t)(b_base + r) * HD + c);
    *(h8*)(h0 + r * 264 + c) = hv;
    unsigned lo = 0, hi = 0;
    lo = __builtin_amdgcn_cvt_pk_fp8_f32((float)hv[0], (float)hv[1], lo, false);
    lo = __builtin_amdgcn_cvt_pk_fp8_f32((float)hv[2], (float)hv[3], lo, true);
    hi = __builtin_amdgcn_cvt_pk_fp8_f32((float)hv[4], (float)hv[5], hi, false);
    hi = __builtin_amdgcn_cvt_pk_fp8_f32((float)hv[6], (float)hv[7], hi, true);
    *(unsigned*)(h80 + r * 264 + c) = lo;
    *(unsigned*)(h80 + r * 264 + c + 4) = hi;
#pragma unroll
    for (int qi = 0; qi < 2; ++qi)
#pragma unroll
      for (int r2 = 0; r2 < 4; ++r2)
        creg[qi * 4 + r2] = ws_c[(size_t)(b_base + quad * 4 + r2) * HD + (2 * w + qi) * 16 + n];
  }
  __syncthreads();

  // ---- precomputed addressing ----
  const int a16_off = n * 264 + quad * 8;           // h fp16 read offset (halfs)
  const int a8_off  = n * 264 + quad * 8;           // h fp8 read offset (bytes)
  const int o8_off0 = (((2 * w + 0) * 8) * 64 + L) * 8;   // o-gate LDS, qi=0, kt=0
  const int o8_off1 = (((2 * w + 1) * 8) * 64 + L) * 8;   // o-gate LDS, qi=1, kt=0
  int loff[8];                                       // xq: ct = gate*2+qi
#pragma unroll
  for (int ct = 0; ct < 8; ++ct) {
    const int g = ct >> 1, qi = ct & 1;
    loff[ct] = ((g * 256 + (2 * w + qi) * 16 + n) << 4) + quad * 4;
  }
  const _Float16* xgp = xg + (size_t)blockIdx.x * (NG * 16);
  float* po[4];
#pragma unroll
  for (int r = 0; r < 4; ++r)
    po[r] = out + ((size_t)(b_base + quad * 4 + r) * T_ALL + t0) * HD + 2 * w * 16 + n;

#pragma unroll 1
  for (int tt = 0; tt < CT; ++tt) {
    const int p = tt & 1;
    const _Float16* hr = (const _Float16*)(smem + SMEM_W8 + p * SMEM_H);
    const unsigned char* h8r = (const unsigned char*)(smem + SMEM_W8 + 2 * SMEM_H + p * SMEM_H8);
    _Float16* hw = (_Float16*)(smem + SMEM_W8 + (p ^ 1) * SMEM_H);
    unsigned char* h8w = (unsigned char*)(smem + SMEM_W8 + 2 * SMEM_H + (p ^ 1) * SMEM_H8);

    h4 xq[8];
#pragma unroll
    for (int ct = 0; ct < 8; ++ct) xq[ct] = *(const h4*)(xgp + loff[ct]);

    f4 aI[2], aF[2], aG[2], aO[2];
#pragma unroll
    for (int qi = 0; qi < 2; ++qi) {
      aI[qi][0]=0.f; aI[qi][1]=0.f; aI[qi][2]=0.f; aI[qi][3]=0.f;
      aF[qi][0]=0.f; aF[qi][1]=0.f; aF[qi][2]=0.f; aF[qi][3]=0.f;
      aG[qi][0]=0.f; aG[qi][1]=0.f; aG[qi][2]=0.f; aG[qi][3]=0.f;
      aO[qi][0]=0.f; aO[qi][1]=0.f; aO[qi][2]=0.f; aO[qi][3]=0.f;
    }

    __builtin_amdgcn_s_setprio(1);
#pragma unroll
    for (int kt = 0; kt < 8; ++kt) {
      h8  a16 = *(const h8*)(hr + a16_off + kt * 32);
      long a8 = *(const long*)(h8r + a8_off + kt * 32);
      long o80 = *(const long*)(w8_lds + o8_off0 + kt * 512);
      long o81 = *(const long*)(w8_lds + o8_off1 + kt * 512);
      aF[0] = __builtin_amdgcn_mfma_f32_16x16x32_f16(a16, bF[0][kt], aF[0], 0, 0, 0);
      aF[1] = __builtin_amdgcn_mfma_f32_16x16x32_f16(a16, bF[1][kt], aF[1], 0, 0, 0);
      aG[0] = __builtin_amdgcn_mfma_f32_16x16x32_f16(a16, bG[0][kt], aG[0], 0, 0, 0);
      aG[1] = __builtin_amdgcn_mfma_f32_16x16x32_f16(a16, bG[1][kt], aG[1], 0, 0, 0);
      aI[0] = __builtin_amdgcn_mfma_f32_16x16x32_fp8_fp8(a8, bI[0][kt], aI[0], 0, 0, 0);
      aI[1] = __builtin_amdgcn_mfma_f32_16x16x32_fp8_fp8(a8, bI[1][kt], aI[1], 0, 0, 0);
      aO[0] = __builtin_amdgcn_mfma_f32_16x16x32_fp8_fp8(a8, o80, aO[0], 0, 0, 0);
      aO[1] = __builtin_amdgcn_mfma_f32_16x16x32_fp8_fp8(a8, o81, aO[1], 0, 0, 0);
    }
    __builtin_amdgcn_s_setprio(0);

    // Epilogue writes go to the OTHER buffer -> no barrier needed before it.
#pragma unroll
    for (int qi = 0; qi < 2; ++qi) {
      const int c_col = (2 * w + qi) * 16 + n;
#pragma unroll
      for (int r = 0; r < 4; ++r) {
        const int row = quad * 4 + r;
        const float vi = aI[qi][r] + (float)xq[0 + qi][r];
        const float vf = aF[qi][r] + (float)xq[2 + qi][r];
        const float vg = aG[qi][r] + (float)xq[4 + qi][r];
        const float vo = aO[qi][r] + (float)xq[6 + qi][r];
        const float cn = sigf(vf) * creg[qi * 4 + r] + sigf(vi) * tanh_f(vg);
        const float hn = sigf(vo) * tanh_f(cn);
        creg[qi * 4 + r] = cn;
        hw[row * 264 + c_col] = (_Float16)hn;
        h8w[row * 264 + c_col] = to_fp8(hn);
        __builtin_nontemporal_store(hn, po[r] + qi * 16);
      }
    }
#pragma unroll
    for (int r = 0; r < 4; ++r) po[r] += HD;
    xgp += 4 * NG * 16;

    // LDS-only drain + raw barrier: do NOT drain vmcnt (global stores/loads have
    // no cross-wave hazard; __syncthreads would force a full vmcnt(0) drain).
    asm volatile("s_waitcnt lgkmcnt(0)" ::: "memory");
    __builtin_amdgcn_s_barrier();
    __builtin_amdgcn_sched_barrier(0);
  }

  { // persist state for next chunk + final h_T/c_T
    const int pf = CT & 1;   // buffer holding h(t0+CT-1)
    const _Float16* hfin = (const _Float16*)(smem + SMEM_W8 + pf * SMEM_H);
    const int idx = tid * 8, r = idx >> 8, c = idx & 255;
    h8 hv = *(const h8*)(hfin + r * 264 + c);
    *(h8*)(ws_h + (size_t)(b_base + r) * HD + c) = hv;
#pragma unroll
    for (int qi = 0; qi < 2; ++qi)
#pragma unroll
      for (int r2 = 0; r2 < 4; ++r2)
        ws_c[(size_t)(b_base + quad * 4 + r2) * HD + (2 * w + qi) * 16 + n] = creg[qi * 4 + r2];

    if (t0 + CT == T_ALL) {
      float* ph = out + HS_N + (size_t)(b_base + r) * HD + c;
#pragma unroll
      for (int j = 0; j < 8; ++j) ph[j] = (float)hv[j];
#pragma unroll
      for (int qi = 0; qi < 2; ++qi)
#pragma unroll
        for (int r2 = 0; r2 < 4; ++r2)
          out[HS_N + (size_t)NBATCH * HD +
              (size_t)(b_base + quad * 4 + r2) * HD + (2 * w + qi) * 16 + n] = creg[qi * 4 + r2];
    }
  }
}

extern "C" void kernel_launch(void* const* d_in, const int* in_sizes, int n_in,
                              void* d_out, int out_size, void* d_ws, size_t ws_size,
                              hipStream_t stream) {
  (void)in_sizes; (void)n_in; (void)out_size;
  const float* x    = (const float*)d_in[0];
  const float* Wi   = (const float*)d_in[1];
  const float* Wh   = (const float*)d_in[2];
  const float* bias = (const float*)d_in[3];
  float* out = (float*)d_out;

  const size_t state_bytes = (size_t)NBATCH * HD * 2 + (size_t)NBATCH * HD * 4;
  int CT = T_ALL;
  while (CT > 32 && (size_t)CT * NG * 64 * 2 + state_bytes > ws_size) CT >>= 1;

  _Float16* xg   = (_Float16*)d_ws;
  _Float16* ws_h = (_Float16*)((char*)d_ws + (size_t)CT * NG * 64 * 2);
  float*    ws_c = (float*)((char*)ws_h + (size_t)NBATCH * HD * 2);

  (void)hipFuncSetAttribute((const void*)lstm_recur,
                            hipFuncAttributeMaxDynamicSharedMemorySize, SMEM_TOTAL);

  for (int t0 = 0; t0 < T_ALL; t0 += CT) {
    lstm_proj<<<dim3(CT), dim3(256), 0, stream>>>(x, Wi, bias, xg, t0);
    lstm_recur<<<dim3(4), dim3(512), SMEM_TOTAL, stream>>>(xg, Wh, out, ws_h, ws_c, t0, CT);
  }
}

// Round 3
// 4678.186 us; speedup vs baseline: 2.0424x; 2.0424x over previous
//
#include <hip/hip_runtime.h>

// LSTM B=64 T=2048 D=H=256.
// lstm_proj: xg[t][bg][j][16b] = x@W_i + bias (fp16, MFMA f16), block-contiguous layout.
// lstm_recur: persistent scan, 8 blocks x 8 batch rows (was 4x16). Weight residency per
// block (CU) — EXACTLY round-1's layout (160-reg layouts spill; VGPR cap is 128 arch):
//   gate i (cols   0..255): fp8 e4m3 in VGPRs (32 regs)
//   gate f (cols 256..511): fp16 in VGPRs (64 regs)
//   gate g (cols 512..767): fp16 in LDS (128 KB)
//   gate o (cols 768..1023): fp8 e4m3 in VGPRs (32 regs)
// Duplicate-row trick: A-fragment row = n&7 -> MFMA rows 8-15 duplicate rows 0-7, so
// lane-quads 2-3 hold copies of quads 0-1's C-fragments. Quads 0-1 run the epilogue for
// qi=0, quads 2-3 for qi=1: 4 outputs/lane instead of 8 -> transcendental VALU halves
// per CU (it was the binding pipe: VALUBusy 0.907, ~80 trans ops/wave/step).
// h double-buffered in LDS as fp16 AND fp8; ONE raw s_barrier per step with
// lgkmcnt(0)-only drain (no vmcnt drain of global out-stores / xq-loads).
// MFMA 16x16x32 (f16 and fp8_fp8): A[m=lane&15][k=(lane>>4)*8+j],
//   B[k][n=lane&15], C row=(lane>>4)*4+reg, col=lane&15.

#define T_ALL 2048
#define NBATCH 64
#define HD 256
#define NG 1024
#define HS_N ((size_t)NBATCH * T_ALL * HD)

typedef _Float16 h8 __attribute__((ext_vector_type(8)));
typedef _Float16 h4 __attribute__((ext_vector_type(4)));
typedef float f4 __attribute__((ext_vector_type(4)));

#define SMEM_W 131072                 // g-gate: 16 tiles x [8kt][64 lanes][8 halfs]
#define SMEM_H 4224                   // h fp16: 8 rows x 264 halfs
#define SMEM_H8 2112                  // h fp8:  8 rows x 264 bytes
#define SMEM_TOTAL (SMEM_W + 2 * SMEM_H + 2 * SMEM_H8)   // 143744 <= 163840

__device__ __forceinline__ float sigf(float x) {
  return __builtin_amdgcn_rcpf(1.f + __expf(-x));
}
__device__ __forceinline__ float tanh_f(float x) {
  return 2.f * __builtin_amdgcn_rcpf(1.f + __expf(-2.f * x)) - 1.f;
}
__device__ __forceinline__ unsigned char to_fp8(float x) {
  return (unsigned char)(__builtin_amdgcn_cvt_pk_fp8_f32(x, x, 0, false) & 0xFF);
}

// ---------------- input projection: one block per timestep ----------------
__global__ __launch_bounds__(256, 2) void lstm_proj(
    const float* __restrict__ x, const float* __restrict__ Wi,
    const float* __restrict__ bias, _Float16* __restrict__ xg, int t0)
{
  const int t = t0 + blockIdx.x;
  const int tid = threadIdx.x;
  const int w = tid >> 6, L = tid & 63;
  const int n = L & 15, quad = L >> 4;

  // B-fragments: x^T[k][b], reused across all j tiles (32 frags = 128 VGPRs)
  h8 bx[8][4];
#pragma unroll
  for (int kt = 0; kt < 8; ++kt) {
#pragma unroll
    for (int bt = 0; bt < 4; ++bt) {
      const int b = bt * 16 + n, k = kt * 32 + quad * 8;
      const float* p = x + ((size_t)b * T_ALL + t) * HD + k;
      f4 lo = *(const f4*)p, hi = *(const f4*)(p + 4);
      h8 f;
      f[0] = (_Float16)lo[0]; f[1] = (_Float16)lo[1];
      f[2] = (_Float16)lo[2]; f[3] = (_Float16)lo[3];
      f[4] = (_Float16)hi[0]; f[5] = (_Float16)hi[1];
      f[6] = (_Float16)hi[2]; f[7] = (_Float16)hi[3];
      bx[kt][bt] = f;
    }
  }

  for (int i = 0; i < 16; ++i) {       // wave w owns j-tiles w*16 .. w*16+15
    const int jt = w * 16 + i;
    float bv0 = bias[jt * 16 + quad * 4 + 0];
    float bv1 = bias[jt * 16 + quad * 4 + 1];
    float bv2 = bias[jt * 16 + quad * 4 + 2];
    float bv3 = bias[jt * 16 + quad * 4 + 3];
    f4 acc[4];
#pragma unroll
    for (int bt = 0; bt < 4; ++bt) {
      acc[bt][0] = bv0; acc[bt][1] = bv1; acc[bt][2] = bv2; acc[bt][3] = bv3;
    }
#pragma unroll
    for (int kt = 0; kt < 8; ++kt) {
      const int j = jt * 16 + n, kb = kt * 32 + quad * 8;
      h8 a;   // A = Wi^T: A[m=j][k=d] = Wi[d][j]
#pragma unroll
      for (int jj = 0; jj < 8; ++jj) a[jj] = (_Float16)Wi[(size_t)(kb + jj) * NG + j];
#pragma unroll
      for (int bt = 0; bt < 4; ++bt)
        acc[bt] = __builtin_amdgcn_mfma_f32_16x16x32_f16(a, bx[kt][bt], acc[bt], 0, 0, 0);
    }
#pragma unroll
    for (int bt = 0; bt < 4; ++bt) {
#pragma unroll
      for (int r = 0; r < 4; ++r) {
        const int j = jt * 16 + quad * 4 + r;   // gate col
        xg[(((size_t)blockIdx.x * 4 + bt) * NG + j) * 16 + n] = (_Float16)acc[bt][r];
      }
    }
  }
}

// ---------------- persistent recurrence: 8 blocks x 8 batch rows ----------------
__global__ __launch_bounds__(512, 2) void lstm_recur(
    const _Float16* __restrict__ xg, const float* __restrict__ Wh,
    float* __restrict__ out, _Float16* __restrict__ ws_h, float* __restrict__ ws_c,
    int t0, int CT)
{
  extern __shared__ char smem[];
  _Float16* w_lds = (_Float16*)smem;                              // g-gate tiles

  const int tid = threadIdx.x;
  const int w = tid >> 6, L = tid & 63;
  const int n = L & 15, quad = L >> 4;
  const int myqi = L >> 5;             // 0 for quads 0-1, 1 for quads 2-3
  const int mrow4 = ((L >> 4) & 1) * 4;
  const int b_base = blockIdx.x * 8;
  const int bb8 = (blockIdx.x & 1) * 8;   // row offset within the 16-batch xg tile

  // ---- load resident weights (one-time, round-1 residency) ----
  h8  bF[2][8];                    // f gate fp16: 64 VGPRs
  long bI[2][8], bO[2][8];         // i / o gates fp8 packed: 32 + 32 VGPRs
#pragma unroll
  for (int qi = 0; qi < 2; ++qi) {
    const int q = 2 * w + qi;
    for (int kt = 0; kt < 8; ++kt) {
      const int kb = kt * 32 + quad * 8;
      { // f gate, fp16 regs
        const int j = 256 + q * 16 + n;
        h8 f;
#pragma unroll
        for (int jj = 0; jj < 8; ++jj) f[jj] = (_Float16)Wh[(size_t)(kb + jj) * NG + j];
        bF[qi][kt] = f;
      }
      { // i gate, fp8 regs
        const int j = 0 + q * 16 + n;
        unsigned lo = 0, hi = 0;
        lo = __builtin_amdgcn_cvt_pk_fp8_f32(Wh[(size_t)(kb + 0) * NG + j], Wh[(size_t)(kb + 1) * NG + j], lo, false);
        lo = __builtin_amdgcn_cvt_pk_fp8_f32(Wh[(size_t)(kb + 2) * NG + j], Wh[(size_t)(kb + 3) * NG + j], lo, true);
        hi = __builtin_amdgcn_cvt_pk_fp8_f32(Wh[(size_t)(kb + 4) * NG + j], Wh[(size_t)(kb + 5) * NG + j], hi, false);
        hi = __builtin_amdgcn_cvt_pk_fp8_f32(Wh[(size_t)(kb + 6) * NG + j], Wh[(size_t)(kb + 7) * NG + j], hi, true);
        bI[qi][kt] = (long)(((unsigned long)hi << 32) | (unsigned long)lo);
      }
      { // o gate, fp8 regs
        const int j = 768 + q * 16 + n;
        unsigned lo = 0, hi = 0;
        lo = __builtin_amdgcn_cvt_pk_fp8_f32(Wh[(size_t)(kb + 0) * NG + j], Wh[(size_t)(kb + 1) * NG + j], lo, false);
        lo = __builtin_amdgcn_cvt_pk_fp8_f32(Wh[(size_t)(kb + 2) * NG + j], Wh[(size_t)(kb + 3) * NG + j], lo, true);
        hi = __builtin_amdgcn_cvt_pk_fp8_f32(Wh[(size_t)(kb + 4) * NG + j], Wh[(size_t)(kb + 5) * NG + j], hi, false);
        hi = __builtin_amdgcn_cvt_pk_fp8_f32(Wh[(size_t)(kb + 6) * NG + j], Wh[(size_t)(kb + 7) * NG + j], hi, true);
        bO[qi][kt] = (long)(((unsigned long)hi << 32) | (unsigned long)lo);
      }
      { // g gate -> LDS
        const int j = 512 + q * 16 + n;
        h8 f;
#pragma unroll
        for (int jj = 0; jj < 8; ++jj) f[jj] = (_Float16)Wh[(size_t)(kb + jj) * NG + j];
        *(h8*)(w_lds + ((size_t)(q * 8 + kt) * 64 + L) * 8) = f;
      }
    }
  }

  // ---- state init / restore (into buffer 0: read buffer of step tt=0) ----
  _Float16* h0 = (_Float16*)(smem + SMEM_W);
  unsigned char* h80 = (unsigned char*)(smem + SMEM_W + 2 * SMEM_H);
  float creg[4];                    // lane-private c: row=mrow4+r, col=(2w+myqi)*16+n
  const int c_col = (2 * w + myqi) * 16 + n;
  if (t0 == 0) {
    for (int i = tid; i < 8 * 264; i += 512) h0[i] = (_Float16)0.f;
    for (int i = tid * 4; i < 8 * 264; i += 512 * 4) *(unsigned*)(h80 + i) = 0u;
#pragma unroll
    for (int i = 0; i < 4; ++i) creg[i] = 0.f;
  } else {
    if (tid < 256) {
      const int idx = tid * 8, r = idx >> 8, c = idx & 255;
      h8 hv = *(const h8*)(ws_h + (size_t)(b_base + r) * HD + c);
      *(h8*)(h0 + r * 264 + c) = hv;
      unsigned lo = 0, hi = 0;
      lo = __builtin_amdgcn_cvt_pk_fp8_f32((float)hv[0], (float)hv[1], lo, false);
      lo = __builtin_amdgcn_cvt_pk_fp8_f32((float)hv[2], (float)hv[3], lo, true);
      hi = __builtin_amdgcn_cvt_pk_fp8_f32((float)hv[4], (float)hv[5], hi, false);
      hi = __builtin_amdgcn_cvt_pk_fp8_f32((float)hv[6], (float)hv[7], hi, true);
      *(unsigned*)(h80 + r * 264 + c) = lo;
      *(unsigned*)(h80 + r * 264 + c + 4) = hi;
    }
#pragma unroll
    for (int r2 = 0; r2 < 4; ++r2)
      creg[r2] = ws_c[(size_t)(b_base + mrow4 + r2) * HD + c_col];
  }
  __syncthreads();

  // ---- precomputed addressing ----
  // A-fragment row = n&7: rows 8-15 duplicate rows 0-7 (same LDS addr -> broadcast).
  const int a16_off = (n & 7) * 264 + quad * 8;     // h fp16 read offset (halfs)
  const int a8_off  = (n & 7) * 264 + quad * 8;     // h fp8 read offset (bytes)
  int loff[4];                                       // xq for THIS lane's qi only
#pragma unroll
  for (int g = 0; g < 4; ++g)
    loff[g] = ((g * 256 + c_col) << 4) + bb8 + mrow4;
  const _Float16* xgp = xg + (size_t)(blockIdx.x >> 1) * (NG * 16);
  float* po[4];
#pragma unroll
  for (int r = 0; r < 4; ++r)
    po[r] = out + ((size_t)(b_base + mrow4 + r) * T_ALL + t0) * HD + c_col;

#pragma unroll 1
  for (int tt = 0; tt < CT; ++tt) {
    const int p = tt & 1;
    const _Float16* hr = (const _Float16*)(smem + SMEM_W + p * SMEM_H);
    const unsigned char* h8r = (const unsigned char*)(smem + SMEM_W + 2 * SMEM_H + p * SMEM_H8);
    _Float16* hw = (_Float16*)(smem + SMEM_W + (p ^ 1) * SMEM_H);
    unsigned char* h8w = (unsigned char*)(smem + SMEM_W + 2 * SMEM_H + (p ^ 1) * SMEM_H8);

    h4 xq[4];
#pragma unroll
    for (int g = 0; g < 4; ++g) xq[g] = *(const h4*)(xgp + loff[g]);

    f4 aI[2], aF[2], aG[2], aO[2];
#pragma unroll
    for (int qi = 0; qi < 2; ++qi) {
      aI[qi][0]=0.f; aI[qi][1]=0.f; aI[qi][2]=0.f; aI[qi][3]=0.f;
      aF[qi][0]=0.f; aF[qi][1]=0.f; aF[qi][2]=0.f; aF[qi][3]=0.f;
      aG[qi][0]=0.f; aG[qi][1]=0.f; aG[qi][2]=0.f; aG[qi][3]=0.f;
      aO[qi][0]=0.f; aO[qi][1]=0.f; aO[qi][2]=0.f; aO[qi][3]=0.f;
    }

    __builtin_amdgcn_s_setprio(1);
#pragma unroll
    for (int kt = 0; kt < 8; ++kt) {
      h8  a16 = *(const h8*)(hr + a16_off + kt * 32);
      long a8 = *(const long*)(h8r + a8_off + kt * 32);
      h8 bg0 = *(const h8*)(w_lds + ((size_t)((2 * w + 0) * 8 + kt) * 64 + L) * 8);
      h8 bg1 = *(const h8*)(w_lds + ((size_t)((2 * w + 1) * 8 + kt) * 64 + L) * 8);
      aF[0] = __builtin_amdgcn_mfma_f32_16x16x32_f16(a16, bF[0][kt], aF[0], 0, 0, 0);
      aF[1] = __builtin_amdgcn_mfma_f32_16x16x32_f16(a16, bF[1][kt], aF[1], 0, 0, 0);
      aG[0] = __builtin_amdgcn_mfma_f32_16x16x32_f16(a16, bg0, aG[0], 0, 0, 0);
      aG[1] = __builtin_amdgcn_mfma_f32_16x16x32_f16(a16, bg1, aG[1], 0, 0, 0);
      aI[0] = __builtin_amdgcn_mfma_f32_16x16x32_fp8_fp8(a8, bI[0][kt], aI[0], 0, 0, 0);
      aI[1] = __builtin_amdgcn_mfma_f32_16x16x32_fp8_fp8(a8, bI[1][kt], aI[1], 0, 0, 0);
      aO[0] = __builtin_amdgcn_mfma_f32_16x16x32_fp8_fp8(a8, bO[0][kt], aO[0], 0, 0, 0);
      aO[1] = __builtin_amdgcn_mfma_f32_16x16x32_fp8_fp8(a8, bO[1][kt], aO[1], 0, 0, 0);
    }
    __builtin_amdgcn_s_setprio(0);

    // C-fragments in quads 2-3 are exact duplicates of quads 0-1 (duplicated A rows),
    // so each lane finishes only its own qi tile: 4 outputs/lane, no shuffles.
    const bool hiq = (L & 32) != 0;
    const f4 sI = hiq ? aI[1] : aI[0];
    const f4 sF = hiq ? aF[1] : aF[0];
    const f4 sG = hiq ? aG[1] : aG[0];
    const f4 sO = hiq ? aO[1] : aO[0];
#pragma unroll
    for (int r = 0; r < 4; ++r) {
      const int row = mrow4 + r;
      const float vi = sI[r] + (float)xq[0][r];
      const float vf = sF[r] + (float)xq[1][r];
      const float vg = sG[r] + (float)xq[2][r];
      const float vo = sO[r] + (float)xq[3][r];
      const float cn = sigf(vf) * creg[r] + sigf(vi) * tanh_f(vg);
      const float hn = sigf(vo) * tanh_f(cn);
      creg[r] = cn;
      hw[row * 264 + c_col] = (_Float16)hn;
      h8w[row * 264 + c_col] = to_fp8(hn);
      __builtin_nontemporal_store(hn, po[r]);
    }
#pragma unroll
    for (int r = 0; r < 4; ++r) po[r] += HD;
    xgp += 4 * NG * 16;

    // LDS-only drain + raw barrier: do NOT drain vmcnt (global stores/loads have
    // no cross-wave hazard; __syncthreads would force a full vmcnt(0) drain).
    asm volatile("s_waitcnt lgkmcnt(0)" ::: "memory");
    __builtin_amdgcn_s_barrier();
    __builtin_amdgcn_sched_barrier(0);
  }

  { // persist state for next chunk + final h_T/c_T
    const int pf = CT & 1;   // buffer holding h(t0+CT-1)
    const _Float16* hfin = (const _Float16*)(smem + SMEM_W + pf * SMEM_H);
    if (tid < 256) {
      const int idx = tid * 8, r = idx >> 8, c = idx & 255;
      h8 hv = *(const h8*)(hfin + r * 264 + c);
      *(h8*)(ws_h + (size_t)(b_base + r) * HD + c) = hv;
      if (t0 + CT == T_ALL) {
        float* ph = out + HS_N + (size_t)(b_base + r) * HD + c;
#pragma unroll
        for (int j = 0; j < 8; ++j) ph[j] = (float)hv[j];
      }
    }
#pragma unroll
    for (int r2 = 0; r2 < 4; ++r2)
      ws_c[(size_t)(b_base + mrow4 + r2) * HD + c_col] = creg[r2];

    if (t0 + CT == T_ALL) {
#pragma unroll
      for (int r2 = 0; r2 < 4; ++r2)
        out[HS_N + (size_t)NBATCH * HD +
            (size_t)(b_base + mrow4 + r2) * HD + c_col] = creg[r2];
    }
  }
}

extern "C" void kernel_launch(void* const* d_in, const int* in_sizes, int n_in,
                              void* d_out, int out_size, void* d_ws, size_t ws_size,
                              hipStream_t stream) {
  (void)in_sizes; (void)n_in; (void)out_size;
  const float* x    = (const float*)d_in[0];
  const float* Wi   = (const float*)d_in[1];
  const float* Wh   = (const float*)d_in[2];
  const float* bias = (const float*)d_in[3];
  float* out = (float*)d_out;

  const size_t state_bytes = (size_t)NBATCH * HD * 2 + (size_t)NBATCH * HD * 4;
  int CT = T_ALL;
  while (CT > 32 && (size_t)CT * NG * 64 * 2 + state_bytes > ws_size) CT >>= 1;

  _Float16* xg   = (_Float16*)d_ws;
  _Float16* ws_h = (_Float16*)((char*)d_ws + (size_t)CT * NG * 64 * 2);
  float*    ws_c = (float*)((char*)ws_h + (size_t)NBATCH * HD * 2);

  (void)hipFuncSetAttribute((const void*)lstm_recur,
                            hipFuncAttributeMaxDynamicSharedMemorySize, SMEM_TOTAL);

  for (int t0 = 0; t0 < T_ALL; t0 += CT) {
    lstm_proj<<<dim3(CT), dim3(256), 0, stream>>>(x, Wi, bias, xg, t0);
    lstm_recur<<<dim3(8), dim3(512), SMEM_TOTAL, stream>>>(xg, Wh, out, ws_h, ws_c, t0, CT);
  }
}